// Round 12
// baseline (107.150 us; speedup 1.0000x reference)
//
#include <hip/hip_runtime.h>
#include <hip/hip_fp16.h>

#define D 64
#define KP 50          // neighbors per row
#define NIT 10000      // R row stride

#define RFL __builtin_amdgcn_readfirstlane

typedef _Float16 half8 __attribute__((ext_vector_type(8)));
typedef float floatx4 __attribute__((ext_vector_type(4)));

__device__ inline float rlanef(float v, int l) {
  return __int_as_float(__builtin_amdgcn_readlane(__float_as_int(v), l));
}

// ---------------- MFMA fragment helpers (16x16x32 f16) --------------------------
__device__ inline half8 loadA_f32(const float* __restrict__ src, int kc,
                                  int lane) {
  const float* p = src + (size_t)(lane & 15) * D + kc * 32 + 8 * (lane >> 4);
  float4 lo = *(const float4*)p;
  float4 hi = *(const float4*)(p + 4);
  half8 a;
  a[0] = (_Float16)lo.x; a[1] = (_Float16)lo.y;
  a[2] = (_Float16)lo.z; a[3] = (_Float16)lo.w;
  a[4] = (_Float16)hi.x; a[5] = (_Float16)hi.y;
  a[6] = (_Float16)hi.z; a[7] = (_Float16)hi.w;
  return a;
}

__device__ inline half8 loadB_f32(const float* __restrict__ W, int kc, int t,
                                  int lane) {
  const float* p =
      W + (size_t)(kc * 32 + 8 * (lane >> 4)) * D + 16 * t + (lane & 15);
  half8 b;
#pragma unroll
  for (int j = 0; j < 8; ++j) b[j] = (_Float16)p[(size_t)j * D];
  return b;
}

// hi/lo split fragments: value = hi + lo to ~2^-22 relative
struct AB { half8 hi, lo; };

__device__ inline AB splitA(const float* src, int stride, int kc, int lane) {
  const float* p =
      src + (size_t)(lane & 15) * stride + kc * 32 + 8 * (lane >> 4);
  AB r;
#pragma unroll
  for (int j = 0; j < 8; ++j) {
    float x = p[j];
    _Float16 h = (_Float16)x;
    r.hi[j] = h;
    r.lo[j] = (_Float16)(x - (float)h);
  }
  return r;
}

__device__ inline AB splitB(const float* __restrict__ W, int kc, int t,
                            int lane) {
  const float* p =
      W + (size_t)(kc * 32 + 8 * (lane >> 4)) * D + 16 * t + (lane & 15);
  AB r;
#pragma unroll
  for (int j = 0; j < 8; ++j) {
    float x = p[(size_t)j * D];
    _Float16 h = (_Float16)x;
    r.hi[j] = h;
    r.lo[j] = (_Float16)(x - (float)h);
  }
  return r;
}

__device__ inline floatx4 mfma3(AB a, AB b, floatx4 acc) {
  acc = __builtin_amdgcn_mfma_f32_16x16x32_f16(a.hi, b.hi, acc, 0, 0, 0);
  acc = __builtin_amdgcn_mfma_f32_16x16x32_f16(a.hi, b.lo, acc, 0, 0, 0);
  acc = __builtin_amdgcn_mfma_f32_16x16x32_f16(a.lo, b.hi, acc, 0, 0, 0);
  return acc;
}

// acc[t] = Asrc(16x64 fp32, row stride As) @ W(64x64 fp32), fp32-class precision
__device__ inline void gemm64(const float* Asrc, int As,
                              const float* __restrict__ W, int lane,
                              floatx4 acc[4]) {
  AB a0 = splitA(Asrc, As, 0, lane);
  AB a1 = splitA(Asrc, As, 1, lane);
#pragma unroll
  for (int t = 0; t < 4; ++t) {
    floatx4 z = {0.f, 0.f, 0.f, 0.f};
    AB b0 = splitB(W, 0, t, lane);
    AB b1 = splitB(W, 1, t, lane);
    z = mfma3(a0, b0, z);
    z = mfma3(a1, b1, z);
    acc[t] = z;
  }
}

// store acc (C layout) into LDS row-major [16][S], bias + optional relu
__device__ inline void cstore(const floatx4 acc[4],
                              const float* __restrict__ bias, bool relu,
                              float* Lb, int S, int lane) {
  const int q = lane >> 4, p = lane & 15;
#pragma unroll
  for (int t = 0; t < 4; ++t) {
    const float bv = bias ? bias[16 * t + p] : 0.f;
#pragma unroll
    for (int i = 0; i < 4; ++i) {
      float v = acc[t][i] + bv;
      Lb[(4 * q + i) * S + 16 * t + p] = relu ? fmaxf(v, 0.f) : v;
    }
  }
}

// ---------------- wave-level helpers (no LDS, no barriers) ----------------------
__device__ inline float score_row_h(const __half* __restrict__ xa,
                                    const float* __restrict__ ia,
                                    const float* __restrict__ w2) {
  float p0 = 0.f, p1 = 0.f;
#pragma unroll
  for (int j = 0; j < D; j += 8) {
    float4 q = *(const float4*)&xa[j];
    const __half2* h2 = (const __half2*)&q;
#pragma unroll
    for (int m = 0; m < 4; ++m) {
      float2 f = __half22float2(h2[m]);
      p0 = fmaf(fmaxf(f.x + ia[j + 2 * m + 0], 0.f), w2[j + 2 * m + 0], p0);
      p1 = fmaf(fmaxf(f.y + ia[j + 2 * m + 1], 0.f), w2[j + 2 * m + 1], p1);
    }
  }
  return p0 + p1;
}

__device__ inline float softmax50(float val, int lane) {
  val = (lane < KP) ? val : -1e30f;
  float m = val;
#pragma unroll
  for (int o = 1; o < 64; o <<= 1) m = fmaxf(m, __shfl_xor(m, o, 64));
  float e = (lane < KP) ? __expf(val - m) : 0.f;
  float s = e;
#pragma unroll
  for (int o = 1; o < 64; o <<= 1) s += __shfl_xor(s, o, 64);
  return e / s;
}

__device__ inline float wsum_rows_h(float a, int ix,
                                    const __half* __restrict__ T, int lane) {
  float v0 = 0.f, v1 = 0.f;
#pragma unroll 10
  for (int k = 0; k < KP; k += 2) {
    const int i0 = __builtin_amdgcn_readlane(ix, k);
    const int i1 = __builtin_amdgcn_readlane(ix, k + 1);
    const float a0 = rlanef(a, k);
    const float a1 = rlanef(a, k + 1);
    v0 = fmaf(a0, (float)T[(size_t)i0 * 128 + 64 + lane], v0);
    v1 = fmaf(a1, (float)T[(size_t)i1 * 128 + 64 + lane], v1);
  }
  return v0 + v1;
}

// ---------------- fused MFMA table kernel ---------------------------------------
#define LSTR 72

__global__ __launch_bounds__(64) void k_tabs(
    const float* __restrict__ item_emb, const float* __restrict__ user_emb,
    const float* __restrict__ op_emb, const float* __restrict__ ia_Wg,
    const float* __restrict__ ia_bg, const float* __restrict__ ua_Wg,
    const float* __restrict__ ua_bg, const float* __restrict__ ia_Wa1,
    const float* __restrict__ ia_ba1, const float* __restrict__ sa_Wa1,
    const float* __restrict__ sa_ba1, const float* __restrict__ ua_Wa1,
    const float* __restrict__ ua_ba1, __half* __restrict__ XXA5,
    __half* __restrict__ FFA5, float* __restrict__ IAu,
    float* __restrict__ SAu, float* __restrict__ UAt, int NU_) {
  __shared__ _Float16 ldsX[16 * LSTR];
  __shared__ _Float16 ldsA[16 * LSTR];
  const int lane = threadIdx.x;
  const int nbl = NU_ >> 4;
  const int s = blockIdx.x / nbl, blk = blockIdx.x % nbl;
  const int g0 = blk * 16;
  const int q = lane >> 4, p = lane & 15;

  if (s >= 2) {
    const float* src = (s == 4) ? item_emb : user_emb;
    const float* W = (s == 2)   ? ia_Wa1 + D * D
                     : (s == 3) ? sa_Wa1 + D * D
                                : ua_Wa1 + D * D;
    const float* bias = (s == 2) ? ia_ba1 : (s == 3) ? sa_ba1 : ua_ba1;
    float* dst = (s == 2) ? IAu : (s == 3) ? SAu : UAt;
    half8 a0 = loadA_f32(src + (size_t)g0 * D, 0, lane);
    half8 a1 = loadA_f32(src + (size_t)g0 * D, 1, lane);
#pragma unroll
    for (int t = 0; t < 4; ++t) {
      floatx4 acc = {0.f, 0.f, 0.f, 0.f};
      half8 b0 = loadB_f32(W, 0, t, lane);
      half8 b1 = loadB_f32(W, 1, t, lane);
      acc = __builtin_amdgcn_mfma_f32_16x16x32_f16(a0, b0, acc, 0, 0, 0);
      acc = __builtin_amdgcn_mfma_f32_16x16x32_f16(a1, b1, acc, 0, 0, 0);
      const float bv = bias[16 * t + p];
#pragma unroll
      for (int i = 0; i < 4; ++i)
        dst[(size_t)(g0 + 4 * q + i) * D + 16 * t + p] = acc[i] + bv;
    }
    return;
  }

  const float* emb = s ? user_emb : item_emb;
  const float* Wg = s ? ua_Wg : ia_Wg;
  const float* bg = s ? ua_bg : ia_bg;
  const float* Wa = s ? ua_Wa1 : ia_Wa1;
  __half* dst = s ? FFA5 : XXA5;

  float opbg[5];
#pragma unroll
  for (int r = 0; r < 5; ++r) opbg[r] = bg[lane];
  for (int j = 0; j < D; ++j) {
    const float w = Wg[(size_t)(D + j) * D + lane];
#pragma unroll
    for (int r = 0; r < 5; ++r) opbg[r] = fmaf(op_emb[r * D + j], w, opbg[r]);
  }

  half8 a0 = loadA_f32(emb + (size_t)g0 * D, 0, lane);
  half8 a1 = loadA_f32(emb + (size_t)g0 * D, 1, lane);
  floatx4 base[4];
  half8 wa[4][2];
#pragma unroll
  for (int t = 0; t < 4; ++t) {
    base[t] = {0.f, 0.f, 0.f, 0.f};
    half8 b0 = loadB_f32(Wg, 0, t, lane);
    half8 b1 = loadB_f32(Wg, 1, t, lane);
    base[t] = __builtin_amdgcn_mfma_f32_16x16x32_f16(a0, b0, base[t], 0, 0, 0);
    base[t] = __builtin_amdgcn_mfma_f32_16x16x32_f16(a1, b1, base[t], 0, 0, 0);
    wa[t][0] = loadB_f32(Wa, 0, t, lane);
    wa[t][1] = loadB_f32(Wa, 1, t, lane);
  }

  for (int r = 0; r < 5; ++r) {
    __syncthreads();  // prior iteration's ldsX/ldsA readers done
#pragma unroll
    for (int t = 0; t < 4; ++t) {
      const float ob = __shfl(opbg[r], p + 16 * t, 64);
#pragma unroll
      for (int i = 0; i < 4; ++i)
        ldsX[(4 * q + i) * LSTR + 16 * t + p] =
            (_Float16)fmaxf(base[t][i] + ob, 0.f);
    }
    __syncthreads();  // ldsX committed before cross-lane reads
    half8 xa0 = *(const half8*)&ldsX[p * LSTR + 0 * 32 + 8 * q];
    half8 xa1 = *(const half8*)&ldsX[p * LSTR + 1 * 32 + 8 * q];
    floatx4 acc[4];
#pragma unroll
    for (int t = 0; t < 4; ++t) {
      acc[t] = {0.f, 0.f, 0.f, 0.f};
      acc[t] = __builtin_amdgcn_mfma_f32_16x16x32_f16(xa0, wa[t][0], acc[t], 0,
                                                      0, 0);
      acc[t] = __builtin_amdgcn_mfma_f32_16x16x32_f16(xa1, wa[t][1], acc[t], 0,
                                                      0, 0);
    }
#pragma unroll
    for (int t = 0; t < 4; ++t)
#pragma unroll
      for (int i = 0; i < 4; ++i)
        ldsA[(4 * q + i) * LSTR + 16 * t + p] = (_Float16)acc[t][i];
    __syncthreads();  // ldsA/ldsX committed before type-punned uint reads
    const uint32_t* srcbuf =
        (lane < 32) ? (const uint32_t*)ldsA : (const uint32_t*)ldsX;
    const int dl = lane & 31;
    for (int m = 0; m < 16; ++m) {
      const uint32_t val = srcbuf[m * (LSTR / 2) + dl];
      uint32_t* rowp = (uint32_t*)(dst + ((size_t)(g0 + m) * 5 + r) * 128);
      rowp[lane] = val;
    }
  }
}

// ---------------- k_hv: item-space aggregation -> Vh (fp32) ---------------------
__global__ __launch_bounds__(256, 8) void k_hv(
    const int* __restrict__ C, const int* __restrict__ Rm,
    const __half* __restrict__ XXA5, const float* __restrict__ IAu,
    const float* __restrict__ ia_Wa2, float* __restrict__ Vh) {
  const int lane = threadIdx.x & 63;
  const int u = RFL(blockIdx.x * 4 + (threadIdx.x >> 6));
  const int kk = lane < KP ? lane : KP - 1;
  const int c = C[u * KP + kk];
  const int ix = c * 5 + Rm[(size_t)u * NIT + c];
  float sc = score_row_h(XXA5 + (size_t)ix * 128, IAu + (size_t)u * D, ia_Wa2);
  float a = softmax50(sc, lane);
  Vh[(size_t)u * D + lane] = wsum_rows_h(a, ix, XXA5, lane);
}

// ---------------- k_hmlp: h = relu(Vh@ia_W+b); HA = h@sa_Wa1 -> HHA -------------
__global__ __launch_bounds__(64) void k_hmlp(const float* __restrict__ Vh,
                                             const float* __restrict__ ia_W,
                                             const float* __restrict__ ia_b,
                                             const float* __restrict__ sa_Wa1,
                                             __half* __restrict__ HHA) {
  __shared__ float Lh[16 * 68];
  __shared__ _Float16 sA[16 * LSTR];
  __shared__ _Float16 sB[16 * LSTR];
  const int lane = threadIdx.x;
  const int g0 = blockIdx.x * 16;
  const int q = lane >> 4, p = lane & 15;
  floatx4 acc[4];
  gemm64(Vh + (size_t)g0 * D, D, ia_W, lane, acc);
  cstore(acc, ia_b, true, Lh, 68, lane);
  __syncthreads();  // Lh committed
  floatx4 acc2[4];
  gemm64(Lh, 68, sa_Wa1, lane, acc2);
#pragma unroll
  for (int t = 0; t < 4; ++t)
#pragma unroll
    for (int i = 0; i < 4; ++i)
      sA[(4 * q + i) * LSTR + 16 * t + p] = (_Float16)acc2[t][i];
  for (int m = 0; m < 16; ++m)
    sB[m * LSTR + lane] = (_Float16)Lh[m * 68 + lane];
  __syncthreads();  // sA/sB committed before type-punned uint reads
  const uint32_t* srcbuf =
      (lane < 32) ? (const uint32_t*)sA : (const uint32_t*)sB;
  const int dl = lane & 31;
  for (int m = 0; m < 16; ++m) {
    const uint32_t val = srcbuf[m * (LSTR / 2) + dl];
    ((uint32_t*)(HHA + (size_t)(g0 + m) * 128))[lane] = val;
  }
}

// ---------------- k_bagg: S and Z aggregations -> VS, VZ (fp32) -----------------
__global__ __launch_bounds__(256, 8) void k_bagg(
    const int* __restrict__ user_idx, const int* __restrict__ item_idx,
    const int* __restrict__ Nn, const int* __restrict__ Bm,
    const int* __restrict__ Rm, const __half* __restrict__ HHA,
    const __half* __restrict__ FFA5, const float* __restrict__ SAu,
    const float* __restrict__ UAt, const float* __restrict__ sa_Wa2,
    const float* __restrict__ ua_Wa2, float* __restrict__ VS,
    float* __restrict__ VZ) {
  const int lane = threadIdx.x & 63;
  const int b = RFL(blockIdx.x * 4 + (threadIdx.x >> 6));
  const int u = RFL(user_idx[b]);
  const int it = RFL(item_idx[b]);
  const int kk = lane < KP ? lane : KP - 1;
  const int nix = Nn[u * KP + kk];
  const int bn = Bm[it * KP + kk];
  const int ix2 = bn * 5 + Rm[(size_t)bn * NIT + it];
  float sc = score_row_h(HHA + (size_t)nix * 128, SAu + (size_t)u * D, sa_Wa2);
  float a = softmax50(sc, lane);
  VS[(size_t)b * D + lane] = wsum_rows_h(a, nix, HHA, lane);
  float sc2 =
      score_row_h(FFA5 + (size_t)ix2 * 128, UAt + (size_t)it * D, ua_Wa2);
  float a2 = softmax50(sc2, lane);
  VZ[(size_t)b * D + lane] = wsum_rows_h(a2, ix2, FFA5, lane);
}

// ---------------- k_bmlp: per-16-rows MFMA MLP chain -> out ---------------------
__global__ __launch_bounds__(64) void k_bmlp(
    const int* __restrict__ user_idx, const float* __restrict__ VS,
    const float* __restrict__ VZ, const __half* __restrict__ HHA,
    const float* __restrict__ sa_W, const float* __restrict__ sa_b,
    const float* __restrict__ ua_W, const float* __restrict__ ua_b,
    const float* __restrict__ fu_W1, const float* __restrict__ fu_b1,
    const float* __restrict__ fu_W2, const float* __restrict__ fu_b2,
    const float* __restrict__ fu_W3, const float* __restrict__ fu_b3,
    const float* __restrict__ rp_W1, const float* __restrict__ rp_b1,
    const float* __restrict__ rp_W2, const float* __restrict__ rp_b2,
    const float* __restrict__ rp_W3, const float* __restrict__ rp_b3,
    float* __restrict__ out) {
  __shared__ float L1[16 * 68];
  __shared__ float L2[16 * 68];
  __shared__ float L3[16 * 68];
  const int lane = threadIdx.x;
  const int r0 = blockIdx.x * 16;
  const int q = lane >> 4, p = lane & 15;
  floatx4 acc[4];
  // hS = relu(VS @ sa_W + sa_b) -> L1
  gemm64(VS + (size_t)r0 * D, D, sa_W, lane, acc);
  cstore(acc, sa_b, true, L1, 68, lane);
  // z = relu(VZ @ ua_W + ua_b) -> L2
  gemm64(VZ + (size_t)r0 * D, D, ua_W, lane, acc);
  cstore(acc, ua_b, true, L2, 68, lane);
  __syncthreads();  // L1/L2 committed
  // hIu A-frags (fp16 exact)
  const int um = user_idx[r0 + p];
  half8 hA0 = *(const half8*)(HHA + (size_t)um * 128 + 64 + 0 * 32 + 8 * q);
  half8 hA1 = *(const half8*)(HHA + (size_t)um * 128 + 64 + 1 * 32 + 8 * q);
  // h1 = relu(cat(hIu, hS) @ fu_W1 + fu_b1) -> L3
  {
    AB a2 = splitA(L1, 68, 0, lane);
    AB a3 = splitA(L1, 68, 1, lane);
#pragma unroll
    for (int t = 0; t < 4; ++t) {
      floatx4 z = {0.f, 0.f, 0.f, 0.f};
      AB b0 = splitB(fu_W1, 0, t, lane);
      AB b1 = splitB(fu_W1, 1, t, lane);
      z = __builtin_amdgcn_mfma_f32_16x16x32_f16(hA0, b0.hi, z, 0, 0, 0);
      z = __builtin_amdgcn_mfma_f32_16x16x32_f16(hA0, b0.lo, z, 0, 0, 0);
      z = __builtin_amdgcn_mfma_f32_16x16x32_f16(hA1, b1.hi, z, 0, 0, 0);
      z = __builtin_amdgcn_mfma_f32_16x16x32_f16(hA1, b1.lo, z, 0, 0, 0);
      AB b2 = splitB(fu_W1 + 64 * D, 0, t, lane);
      AB b3 = splitB(fu_W1 + 64 * D, 1, t, lane);
      z = mfma3(a2, b2, z);
      z = mfma3(a3, b3, z);
      acc[t] = z;
    }
    __syncthreads();
    cstore(acc, fu_b1, true, L3, 68, lane);
  }
  __syncthreads();  // L3 committed
  // h2 = relu(L3 @ fu_W2 + fu_b2) -> L1
  gemm64(L3, 68, fu_W2, lane, acc);
  __syncthreads();  // L1 readers (none pending) / order L1 rewrite
  cstore(acc, fu_b2, true, L1, 68, lane);
  __syncthreads();
  // h3 = relu(L1 @ fu_W3 + fu_b3) -> L3
  gemm64(L1, 68, fu_W3, lane, acc);
  __syncthreads();
  cstore(acc, fu_b3, true, L3, 68, lane);
  __syncthreads();
  // g1 = relu(cat(h3, z) @ rp_W1 + rp_b1) -> L1
  {
    AB a0 = splitA(L3, 68, 0, lane);
    AB a1 = splitA(L3, 68, 1, lane);
    AB a2 = splitA(L2, 68, 0, lane);
    AB a3 = splitA(L2, 68, 1, lane);
#pragma unroll
    for (int t = 0; t < 4; ++t) {
      floatx4 z = {0.f, 0.f, 0.f, 0.f};
      AB b0 = splitB(rp_W1, 0, t, lane);
      AB b1 = splitB(rp_W1, 1, t, lane);
      AB b2 = splitB(rp_W1 + 64 * D, 0, t, lane);
      AB b3 = splitB(rp_W1 + 64 * D, 1, t, lane);
      z = mfma3(a0, b0, z);
      z = mfma3(a1, b1, z);
      z = mfma3(a2, b2, z);
      z = mfma3(a3, b3, z);
      acc[t] = z;
    }
    __syncthreads();
    cstore(acc, rp_b1, true, L1, 68, lane);
  }
  __syncthreads();
  // g2 = relu(L1 @ rp_W2 + rp_b2) -> L3
  gemm64(L1, 68, rp_W2, lane, acc);
  __syncthreads();
  cstore(acc, rp_b2, true, L3, 68, lane);
  __syncthreads();  // L3 committed before final dot
  // out[r0+m] = dot(L3[m], rp_W3) + rp_b3
  float pp = 0.f;
#pragma unroll
  for (int j = 0; j < 16; ++j)
    pp = fmaf(L3[p * 68 + 16 * q + j], rp_W3[16 * q + j], pp);
  pp += __shfl_xor(pp, 16, 64);
  pp += __shfl_xor(pp, 32, 64);
  if (lane < 16) out[r0 + lane] = pp + rp_b3[0];
}

extern "C" void kernel_launch(void* const* d_in, const int* in_sizes, int n_in,
                              void* d_out, int out_size, void* d_ws,
                              size_t ws_size, hipStream_t stream) {
  const int* user_idx = (const int*)d_in[0];
  const int* item_idx = (const int*)d_in[1];
  const int* C = (const int*)d_in[2];
  const int* Nn = (const int*)d_in[3];
  const int* Bm = (const int*)d_in[4];
  const int* Rm = (const int*)d_in[5];
  const float* user_emb = (const float*)d_in[6];
  const float* item_emb = (const float*)d_in[7];
  const float* opinion_emb = (const float*)d_in[8];
  const float* ia_Wg = (const float*)d_in[9];
  const float* ia_bg = (const float*)d_in[10];
  const float* ua_Wg = (const float*)d_in[11];
  const float* ua_bg = (const float*)d_in[12];
  const float* ia_Wa1 = (const float*)d_in[13];
  const float* ia_ba1 = (const float*)d_in[14];
  const float* ia_Wa2 = (const float*)d_in[15];
  const float* ia_W = (const float*)d_in[17];
  const float* ia_b = (const float*)d_in[18];
  const float* sa_Wa1 = (const float*)d_in[19];
  const float* sa_ba1 = (const float*)d_in[20];
  const float* sa_Wa2 = (const float*)d_in[21];
  const float* sa_W = (const float*)d_in[23];
  const float* sa_b = (const float*)d_in[24];
  const float* ua_Wa1 = (const float*)d_in[25];
  const float* ua_ba1 = (const float*)d_in[26];
  const float* ua_Wa2 = (const float*)d_in[27];
  const float* ua_W = (const float*)d_in[29];
  const float* ua_b = (const float*)d_in[30];
  const float* fu_W1 = (const float*)d_in[31];
  const float* fu_b1 = (const float*)d_in[32];
  const float* fu_W2 = (const float*)d_in[33];
  const float* fu_b2 = (const float*)d_in[34];
  const float* rp_W1 = (const float*)d_in[35];
  const float* rp_b1 = (const float*)d_in[36];
  const float* rp_W2 = (const float*)d_in[37];
  const float* rp_b2 = (const float*)d_in[38];
  const float* fu_W3 = (const float*)d_in[39];
  const float* fu_b3 = (const float*)d_in[40];
  const float* rp_W3 = (const float*)d_in[41];
  const float* rp_b3 = (const float*)d_in[42];

  const int NU = in_sizes[6] / D;  // 10000 users
  const int B = in_sizes[0];       // 2048

  __half* XXA5 = (__half*)d_ws;                   // NU*5*128 halves
  __half* FFA5 = XXA5 + (size_t)NU * 5 * 128;     // NU*5*128 halves
  __half* HHA = FFA5 + (size_t)NU * 5 * 128;      // NU*128 halves
  float* IAu = (float*)(HHA + (size_t)NU * 128);  // NU*D fp32
  float* SAu = IAu + (size_t)NU * D;
  float* UAt = SAu + (size_t)NU * D;
  float* Vh = UAt + (size_t)NU * D;               // NU*D fp32
  float* VS = Vh + (size_t)NU * D;                // B*D fp32
  float* VZ = VS + (size_t)B * D;                 // B*D fp32

  const int nbl = NU / 16;  // 625

  k_tabs<<<5 * nbl, 64, 0, stream>>>(item_emb, user_emb, opinion_emb, ia_Wg,
                                     ia_bg, ua_Wg, ua_bg, ia_Wa1, ia_ba1,
                                     sa_Wa1, sa_ba1, ua_Wa1, ua_ba1, XXA5,
                                     FFA5, IAu, SAu, UAt, NU);
  k_hv<<<NU / 4, 256, 0, stream>>>(C, Rm, XXA5, IAu, ia_Wa2, Vh);
  k_hmlp<<<nbl, 64, 0, stream>>>(Vh, ia_W, ia_b, sa_Wa1, HHA);
  k_bagg<<<B / 4, 256, 0, stream>>>(user_idx, item_idx, Nn, Bm, Rm, HHA, FFA5,
                                    SAu, UAt, sa_Wa2, ua_Wa2, VS, VZ);
  k_bmlp<<<B / 16, 64, 0, stream>>>(user_idx, VS, VZ, HHA, sa_W, sa_b, ua_W,
                                    ua_b, fu_W1, fu_b1, fu_W2, fu_b2, fu_W3,
                                    fu_b3, rp_W1, rp_b1, rp_W2, rp_b2, rp_W3,
                                    rp_b3, (float*)d_out);
}

// Round 13
// 90.450 us; speedup vs baseline: 1.1846x; 1.1846x over previous
//
#include <hip/hip_runtime.h>
#include <hip/hip_fp16.h>

#define D 64
#define KP 50          // neighbors per row
#define NIT 10000      // R row stride

#define RFL __builtin_amdgcn_readfirstlane

typedef _Float16 half8 __attribute__((ext_vector_type(8)));
typedef float floatx4 __attribute__((ext_vector_type(4)));

__device__ inline float rlanef(float v, int l) {
  return __int_as_float(__builtin_amdgcn_readlane(__float_as_int(v), l));
}

// ---------------- MFMA fragment helpers (16x16x32 f16) --------------------------
// A-frag: lane l holds A[m = l&15][k = kc*32 + 8*(l>>4) + j], j=0..7  (fp32 src)
__device__ inline half8 loadA_f32(const float* __restrict__ src, int kc,
                                  int lane) {
  const float* p = src + (size_t)(lane & 15) * D + kc * 32 + 8 * (lane >> 4);
  float4 lo = *(const float4*)p;
  float4 hi = *(const float4*)(p + 4);
  half8 a;
  a[0] = (_Float16)lo.x; a[1] = (_Float16)lo.y;
  a[2] = (_Float16)lo.z; a[3] = (_Float16)lo.w;
  a[4] = (_Float16)hi.x; a[5] = (_Float16)hi.y;
  a[6] = (_Float16)hi.z; a[7] = (_Float16)hi.w;
  return a;
}

// B-frag: lane l holds B[k = kc*32 + 8*(l>>4)+j][n = 16*t + (l&15)]  (fp32 W, ld=D)
__device__ inline half8 loadB_f32(const float* __restrict__ W, int kc, int t,
                                  int lane) {
  const float* p =
      W + (size_t)(kc * 32 + 8 * (lane >> 4)) * D + 16 * t + (lane & 15);
  half8 b;
#pragma unroll
  for (int j = 0; j < 8; ++j) b[j] = (_Float16)p[(size_t)j * D];
  return b;
}

// ---------------- wave-level helpers (no LDS, no barriers) ----------------------
__device__ inline float score_row_h(const __half* __restrict__ xa,
                                    const float* __restrict__ ia,
                                    const float* __restrict__ w2) {
  float p0 = 0.f, p1 = 0.f;
#pragma unroll
  for (int j = 0; j < D; j += 8) {
    float4 q = *(const float4*)&xa[j];
    const __half2* h2 = (const __half2*)&q;
#pragma unroll
    for (int m = 0; m < 4; ++m) {
      float2 f = __half22float2(h2[m]);
      p0 = fmaf(fmaxf(f.x + ia[j + 2 * m + 0], 0.f), w2[j + 2 * m + 0], p0);
      p1 = fmaf(fmaxf(f.y + ia[j + 2 * m + 1], 0.f), w2[j + 2 * m + 1], p1);
    }
  }
  return p0 + p1;
}

__device__ inline float softmax50(float val, int lane) {
  val = (lane < KP) ? val : -1e30f;
  float m = val;
#pragma unroll
  for (int o = 1; o < 64; o <<= 1) m = fmaxf(m, __shfl_xor(m, o, 64));
  float e = (lane < KP) ? __expf(val - m) : 0.f;
  float s = e;
#pragma unroll
  for (int o = 1; o < 64; o <<= 1) s += __shfl_xor(s, o, 64);
  return e / s;
}

__device__ inline float wsum_rows_h(float a, int ix,
                                    const __half* __restrict__ T, int lane) {
  float v0 = 0.f, v1 = 0.f;
#pragma unroll 10
  for (int k = 0; k < KP; k += 2) {
    const int i0 = __builtin_amdgcn_readlane(ix, k);
    const int i1 = __builtin_amdgcn_readlane(ix, k + 1);
    const float a0 = rlanef(a, k);
    const float a1 = rlanef(a, k + 1);
    v0 = fmaf(a0, (float)T[(size_t)i0 * 128 + 64 + lane], v0);
    v1 = fmaf(a1, (float)T[(size_t)i1 * 128 + 64 + lane], v1);
  }
  return v0 + v1;
}

template <bool RELU>
__device__ inline float mv64b(float vin, const float* __restrict__ W,
                              const float* __restrict__ bias, int lane) {
  float acc = bias[lane];
#pragma unroll 8
  for (int j = 0; j < D; ++j)
    acc = fmaf(rlanef(vin, j), W[j * D + lane], acc);
  return RELU ? fmaxf(acc, 0.f) : acc;
}

__device__ inline float mv128b(float lo, float hi, const float* __restrict__ W,
                               const float* __restrict__ bias, int lane) {
  float acc = bias[lane];
#pragma unroll 8
  for (int j = 0; j < D; ++j)
    acc = fmaf(rlanef(lo, j), W[j * D + lane], acc);
#pragma unroll 8
  for (int j = 0; j < D; ++j)
    acc = fmaf(rlanef(hi, j), W[(D + j) * D + lane], acc);
  return fmaxf(acc, 0.f);
}

// ---------------- fused MFMA table kernel ---------------------------------------
// grid = 2 * (NU/16) single-wave blocks.
//  s=0: item gate -> XXA5 rows + UAt      s=1: user gate -> FFA5 rows + IAu, SAu
#define LSTR 72  // padded LDS row stride in halves (144B)

__global__ __launch_bounds__(64) void k_tabs(
    const float* __restrict__ item_emb, const float* __restrict__ user_emb,
    const float* __restrict__ op_emb, const float* __restrict__ ia_Wg,
    const float* __restrict__ ia_bg, const float* __restrict__ ua_Wg,
    const float* __restrict__ ua_bg, const float* __restrict__ ia_Wa1,
    const float* __restrict__ ia_ba1, const float* __restrict__ sa_Wa1,
    const float* __restrict__ sa_ba1, const float* __restrict__ ua_Wa1,
    const float* __restrict__ ua_ba1, __half* __restrict__ XXA5,
    __half* __restrict__ FFA5, float* __restrict__ IAu,
    float* __restrict__ SAu, float* __restrict__ UAt, int NU_) {
  __shared__ _Float16 ldsX[16 * LSTR];
  __shared__ _Float16 ldsA[16 * LSTR];
  const int lane = threadIdx.x;
  const int nbl = NU_ >> 4;
  const int s = blockIdx.x / nbl, blk = blockIdx.x % nbl;
  const int g0 = blk * 16;
  const int q = lane >> 4, p = lane & 15;

  const float* emb = s ? user_emb : item_emb;
  const float* Wg = s ? ua_Wg : ia_Wg;
  const float* bg = s ? ua_bg : ia_bg;
  const float* Wa = s ? ua_Wa1 : ia_Wa1;  // low 64 rows
  __half* dst = s ? FFA5 : XXA5;

  // A-fragments of this block's 16 emb rows (shared by all outputs)
  half8 a0 = loadA_f32(emb + (size_t)g0 * D, 0, lane);
  half8 a1 = loadA_f32(emb + (size_t)g0 * D, 1, lane);

  // ---- fused extra outputs (share a0/a1) ----
  if (s == 0) {
    // UAt = item_emb @ ua_Wa1_hi + ua_ba1
#pragma unroll
    for (int t = 0; t < 4; ++t) {
      floatx4 acc = {0.f, 0.f, 0.f, 0.f};
      half8 b0 = loadB_f32(ua_Wa1 + D * D, 0, t, lane);
      half8 b1 = loadB_f32(ua_Wa1 + D * D, 1, t, lane);
      acc = __builtin_amdgcn_mfma_f32_16x16x32_f16(a0, b0, acc, 0, 0, 0);
      acc = __builtin_amdgcn_mfma_f32_16x16x32_f16(a1, b1, acc, 0, 0, 0);
      const float bv = ua_ba1[16 * t + p];
#pragma unroll
      for (int i = 0; i < 4; ++i)
        UAt[(size_t)(g0 + 4 * q + i) * D + 16 * t + p] = acc[i] + bv;
    }
  } else {
    // IAu = user_emb @ ia_Wa1_hi + ia_ba1 ; SAu = user_emb @ sa_Wa1_hi + sa_ba1
#pragma unroll
    for (int t = 0; t < 4; ++t) {
      floatx4 acc = {0.f, 0.f, 0.f, 0.f};
      half8 b0 = loadB_f32(ia_Wa1 + D * D, 0, t, lane);
      half8 b1 = loadB_f32(ia_Wa1 + D * D, 1, t, lane);
      acc = __builtin_amdgcn_mfma_f32_16x16x32_f16(a0, b0, acc, 0, 0, 0);
      acc = __builtin_amdgcn_mfma_f32_16x16x32_f16(a1, b1, acc, 0, 0, 0);
      const float bv = ia_ba1[16 * t + p];
#pragma unroll
      for (int i = 0; i < 4; ++i)
        IAu[(size_t)(g0 + 4 * q + i) * D + 16 * t + p] = acc[i] + bv;
    }
#pragma unroll
    for (int t = 0; t < 4; ++t) {
      floatx4 acc = {0.f, 0.f, 0.f, 0.f};
      half8 b0 = loadB_f32(sa_Wa1 + D * D, 0, t, lane);
      half8 b1 = loadB_f32(sa_Wa1 + D * D, 1, t, lane);
      acc = __builtin_amdgcn_mfma_f32_16x16x32_f16(a0, b0, acc, 0, 0, 0);
      acc = __builtin_amdgcn_mfma_f32_16x16x32_f16(a1, b1, acc, 0, 0, 0);
      const float bv = sa_ba1[16 * t + p];
#pragma unroll
      for (int i = 0; i < 4; ++i)
        SAu[(size_t)(g0 + 4 * q + i) * D + 16 * t + p] = acc[i] + bv;
    }
  }

  // ---- opbg[r] = bg + op_emb[r] @ Wg_hi  (per-lane d = lane) ----
  float opbg[5];
#pragma unroll
  for (int r = 0; r < 5; ++r) opbg[r] = bg[lane];
  for (int j = 0; j < D; ++j) {
    const float w = Wg[(size_t)(D + j) * D + lane];
#pragma unroll
    for (int r = 0; r < 5; ++r) opbg[r] = fmaf(op_emb[r * D + j], w, opbg[r]);
  }

  // ---- base = emb16x64 @ Wg_lo ; preload Wa B-frags ----
  floatx4 base[4];
  half8 wa[4][2];
#pragma unroll
  for (int t = 0; t < 4; ++t) {
    base[t] = {0.f, 0.f, 0.f, 0.f};
    half8 b0 = loadB_f32(Wg, 0, t, lane);
    half8 b1 = loadB_f32(Wg, 1, t, lane);
    base[t] = __builtin_amdgcn_mfma_f32_16x16x32_f16(a0, b0, base[t], 0, 0, 0);
    base[t] = __builtin_amdgcn_mfma_f32_16x16x32_f16(a1, b1, base[t], 0, 0, 0);
    wa[t][0] = loadB_f32(Wa, 0, t, lane);
    wa[t][1] = loadB_f32(Wa, 1, t, lane);
  }

  for (int r = 0; r < 5; ++r) {
    __syncthreads();  // prior iteration's ldsX/ldsA readers done
#pragma unroll
    for (int t = 0; t < 4; ++t) {
      const float ob = __shfl(opbg[r], p + 16 * t, 64);
#pragma unroll
      for (int i = 0; i < 4; ++i)
        ldsX[(4 * q + i) * LSTR + 16 * t + p] =
            (_Float16)fmaxf(base[t][i] + ob, 0.f);
    }
    __syncthreads();  // ldsX committed before cross-lane reads
    half8 xa0 = *(const half8*)&ldsX[p * LSTR + 0 * 32 + 8 * q];
    half8 xa1 = *(const half8*)&ldsX[p * LSTR + 1 * 32 + 8 * q];
    floatx4 acc[4];
#pragma unroll
    for (int t = 0; t < 4; ++t) {
      acc[t] = {0.f, 0.f, 0.f, 0.f};
      acc[t] = __builtin_amdgcn_mfma_f32_16x16x32_f16(xa0, wa[t][0], acc[t], 0,
                                                      0, 0);
      acc[t] = __builtin_amdgcn_mfma_f32_16x16x32_f16(xa1, wa[t][1], acc[t], 0,
                                                      0, 0);
    }
#pragma unroll
    for (int t = 0; t < 4; ++t)
#pragma unroll
      for (int i = 0; i < 4; ++i)
        ldsA[(4 * q + i) * LSTR + 16 * t + p] = (_Float16)acc[t][i];
    __syncthreads();  // ldsA/ldsX committed before type-punned uint reads
    const uint32_t* srcbuf =
        (lane < 32) ? (const uint32_t*)ldsA : (const uint32_t*)ldsX;
    const int dl = lane & 31;
    for (int m = 0; m < 16; ++m) {
      const uint32_t val = srcbuf[m * (LSTR / 2) + dl];
      uint32_t* rowp = (uint32_t*)(dst + ((size_t)(g0 + m) * 5 + r) * 128);
      rowp[lane] = val;
    }
  }
}

// ---------------- h_I_all: one wave per user, zero barriers ---------------------
__global__ __launch_bounds__(256, 8) void k_hIall(
    const int* __restrict__ C, const int* __restrict__ Rm,
    const __half* __restrict__ XXA5, const float* __restrict__ IAu,
    const float* __restrict__ ia_Wa2, const float* __restrict__ ia_W,
    const float* __restrict__ ia_b, const float* __restrict__ sa_Wa1,
    __half* __restrict__ HHA) {
  const int lane = threadIdx.x & 63;
  const int u = RFL(blockIdx.x * 4 + (threadIdx.x >> 6));
  const int kk = lane < KP ? lane : KP - 1;
  const int c = C[u * KP + kk];
  const int ix = c * 5 + Rm[(size_t)u * NIT + c];  // random HBM gather
  float sc = score_row_h(XXA5 + (size_t)ix * 128, IAu + (size_t)u * D, ia_Wa2);
  float a = softmax50(sc, lane);
  float v = wsum_rows_h(a, ix, XXA5, lane);
  float h = mv64b<true>(v, ia_W, ia_b, lane);
  float ha = 0.f;
#pragma unroll 8
  for (int j = 0; j < D; ++j)
    ha = fmaf(rlanef(h, j), sa_Wa1[j * D + lane], ha);
  HHA[(size_t)u * 128 + lane] = __float2half(ha);      // HA half (score)
  HHA[(size_t)u * 128 + 64 + lane] = __float2half(h);  // hI half (wsum/MLP)
}

// ---------------- batch: one wave per row, zero barriers ------------------------
__global__ __launch_bounds__(256, 8) void k_batch(
    const int* __restrict__ user_idx, const int* __restrict__ item_idx,
    const int* __restrict__ Nn, const int* __restrict__ Bm,
    const int* __restrict__ Rm, const __half* __restrict__ HHA,
    const __half* __restrict__ FFA5, const float* __restrict__ SAu,
    const float* __restrict__ UAt, const float* __restrict__ sa_Wa2,
    const float* __restrict__ sa_W, const float* __restrict__ sa_b,
    const float* __restrict__ ua_Wa2, const float* __restrict__ ua_W,
    const float* __restrict__ ua_b, const float* __restrict__ fu_W1,
    const float* __restrict__ fu_b1, const float* __restrict__ fu_W2,
    const float* __restrict__ fu_b2, const float* __restrict__ fu_W3,
    const float* __restrict__ fu_b3, const float* __restrict__ rp_W1,
    const float* __restrict__ rp_b1, const float* __restrict__ rp_W2,
    const float* __restrict__ rp_b2, const float* __restrict__ rp_W3,
    const float* __restrict__ rp_b3, float* __restrict__ out) {
  const int lane = threadIdx.x & 63;
  const int b = RFL(blockIdx.x * 4 + (threadIdx.x >> 6));
  const int u = RFL(user_idx[b]);
  const int it = RFL(item_idx[b]);
  const int kk = lane < KP ? lane : KP - 1;
  const int nix = Nn[u * KP + kk];
  const int bn = Bm[it * KP + kk];
  const int ix2 = bn * 5 + Rm[(size_t)bn * NIT + it];
  const float hIu = (float)HHA[(size_t)u * 128 + 64 + lane];
  // ---- phase S ----
  float sc = score_row_h(HHA + (size_t)nix * 128, SAu + (size_t)u * D, sa_Wa2);
  float a = softmax50(sc, lane);
  float v = wsum_rows_h(a, nix, HHA, lane);
  float hS = mv64b<true>(v, sa_W, sa_b, lane);
  // ---- phase Z ----
  float sc2 =
      score_row_h(FFA5 + (size_t)ix2 * 128, UAt + (size_t)it * D, ua_Wa2);
  float a2 = softmax50(sc2, lane);
  float v2 = wsum_rows_h(a2, ix2, FFA5, lane);
  float z = mv64b<true>(v2, ua_W, ua_b, lane);
  // ---- fu MLP ----
  float h = mv128b(hIu, hS, fu_W1, fu_b1, lane);
  h = mv64b<true>(h, fu_W2, fu_b2, lane);
  h = mv64b<true>(h, fu_W3, fu_b3, lane);
  // ---- rp MLP ----
  float g = mv128b(h, z, rp_W1, rp_b1, lane);
  g = mv64b<true>(g, rp_W2, rp_b2, lane);
  float pp = g * rp_W3[lane];
#pragma unroll
  for (int o = 1; o < 64; o <<= 1) pp += __shfl_xor(pp, o, 64);
  if (lane == 0) out[b] = pp + rp_b3[0];
}

extern "C" void kernel_launch(void* const* d_in, const int* in_sizes, int n_in,
                              void* d_out, int out_size, void* d_ws,
                              size_t ws_size, hipStream_t stream) {
  const int* user_idx = (const int*)d_in[0];
  const int* item_idx = (const int*)d_in[1];
  const int* C = (const int*)d_in[2];
  const int* Nn = (const int*)d_in[3];
  const int* Bm = (const int*)d_in[4];
  const int* Rm = (const int*)d_in[5];
  const float* user_emb = (const float*)d_in[6];
  const float* item_emb = (const float*)d_in[7];
  const float* opinion_emb = (const float*)d_in[8];
  const float* ia_Wg = (const float*)d_in[9];
  const float* ia_bg = (const float*)d_in[10];
  const float* ua_Wg = (const float*)d_in[11];
  const float* ua_bg = (const float*)d_in[12];
  const float* ia_Wa1 = (const float*)d_in[13];
  const float* ia_ba1 = (const float*)d_in[14];
  const float* ia_Wa2 = (const float*)d_in[15];
  const float* ia_W = (const float*)d_in[17];
  const float* ia_b = (const float*)d_in[18];
  const float* sa_Wa1 = (const float*)d_in[19];
  const float* sa_ba1 = (const float*)d_in[20];
  const float* sa_Wa2 = (const float*)d_in[21];
  const float* sa_W = (const float*)d_in[23];
  const float* sa_b = (const float*)d_in[24];
  const float* ua_Wa1 = (const float*)d_in[25];
  const float* ua_ba1 = (const float*)d_in[26];
  const float* ua_Wa2 = (const float*)d_in[27];
  const float* ua_W = (const float*)d_in[29];
  const float* ua_b = (const float*)d_in[30];
  const float* fu_W1 = (const float*)d_in[31];
  const float* fu_b1 = (const float*)d_in[32];
  const float* fu_W2 = (const float*)d_in[33];
  const float* fu_b2 = (const float*)d_in[34];
  const float* rp_W1 = (const float*)d_in[35];
  const float* rp_b1 = (const float*)d_in[36];
  const float* rp_W2 = (const float*)d_in[37];
  const float* rp_b2 = (const float*)d_in[38];
  const float* fu_W3 = (const float*)d_in[39];
  const float* fu_b3 = (const float*)d_in[40];
  const float* rp_W3 = (const float*)d_in[41];
  const float* rp_b3 = (const float*)d_in[42];

  const int NU = in_sizes[6] / D;  // 10000 users
  const int B = in_sizes[0];       // 2048

  __half* XXA5 = (__half*)d_ws;                   // NU*5*128 halves
  __half* FFA5 = XXA5 + (size_t)NU * 5 * 128;     // NU*5*128 halves
  __half* HHA = FFA5 + (size_t)NU * 5 * 128;      // NU*128 halves
  float* IAu = (float*)(HHA + (size_t)NU * 128);  // NU*D fp32
  float* SAu = IAu + (size_t)NU * D;
  float* UAt = SAu + (size_t)NU * D;

  const int nbl = NU / 16;  // 625

  k_tabs<<<2 * nbl, 64, 0, stream>>>(item_emb, user_emb, opinion_emb, ia_Wg,
                                     ia_bg, ua_Wg, ua_bg, ia_Wa1, ia_ba1,
                                     sa_Wa1, sa_ba1, ua_Wa1, ua_ba1, XXA5,
                                     FFA5, IAu, SAu, UAt, NU);
  k_hIall<<<NU / 4, 256, 0, stream>>>(C, Rm, XXA5, IAu, ia_Wa2, ia_W, ia_b,
                                      sa_Wa1, HHA);
  k_batch<<<B / 4, 256, 0, stream>>>(user_idx, item_idx, Nn, Bm, Rm, HHA, FFA5,
                                     SAu, UAt, sa_Wa2, sa_W, sa_b, ua_Wa2,
                                     ua_W, ua_b, fu_W1, fu_b1, fu_W2, fu_b2,
                                     fu_W3, fu_b3, rp_W1, rp_b1, rp_W2, rp_b2,
                                     rp_W3, rp_b3, (float*)d_out);
}